// Round 1
// baseline (223.154 us; speedup 1.0000x reference)
//
#include <hip/hip_runtime.h>
#include <hip/hip_bf16.h>

// Problem constants
#define NROWS 8192   // 2B
#define BHALF 4096   // B
#define DDIM  512    // D

// GEMM tiling
#define BM 128
#define BN 128
#define BK 64
#define CHUNK 4                          // col-tiles per block
#define NCHUNKS (NROWS / BN / CHUNK)     // 16
#define GRID2 ((NROWS / BM) * NCHUNKS)   // 1024

// sqrt(1/0.07): fold temperature into the normalized features so the MFMA
// accumulator is already sim/T.
#define FSCALE 3.7796447300922722f

typedef short bf16x8 __attribute__((ext_vector_type(8)));          // 8 bf16 (4 VGPRs)
typedef float f32x4 __attribute__((ext_vector_type(4)));
typedef unsigned short u16x8 __attribute__((ext_vector_type(8)));
typedef __attribute__((address_space(1))) unsigned int gu32;
typedef __attribute__((address_space(3))) unsigned int lu32;

// ---------------------------------------------------------------------------
// Kernel 1: L2-normalize each row of concat([logits, label]) and store
// bf16( x / ||x|| * sqrt(1/T) ) into fn[8192][512].
// ---------------------------------------------------------------------------
__global__ __launch_bounds__(64) void normalize_kernel(
    const float* __restrict__ logits, const float* __restrict__ label,
    unsigned short* __restrict__ fn) {
  const int row = blockIdx.x;
  const int lane = threadIdx.x;
  const float* src = (row < BHALF) ? (logits + (size_t)row * DDIM)
                                   : (label + (size_t)(row - BHALF) * DDIM);
  const float4* s4 = (const float4*)src;
  float4 a = s4[lane * 2 + 0];
  float4 b = s4[lane * 2 + 1];
  float ss = a.x * a.x + a.y * a.y + a.z * a.z + a.w * a.w +
             b.x * b.x + b.y * b.y + b.z * b.z + b.w * b.w;
#pragma unroll
  for (int m = 1; m < 64; m <<= 1) ss += __shfl_xor(ss, m);
  const float inv = FSCALE / fmaxf(sqrtf(ss), 1e-12f);
  const float v[8] = {a.x, a.y, a.z, a.w, b.x, b.y, b.z, b.w};
  u16x8 o;
#pragma unroll
  for (int j = 0; j < 8; ++j) {
    float x = v[j] * inv;
    unsigned u = __float_as_uint(x);
    unsigned r = (u + 0x7fffu + ((u >> 16) & 1u)) >> 16;  // RNE to bf16
    o[j] = (unsigned short)r;
  }
  *(u16x8*)(fn + (size_t)row * DDIM + lane * 8) = o;
}

// ---------------------------------------------------------------------------
// Kernel 2: fused sim = Fn*Fn^T (already scaled by 1/T), exp, masked per-row
// sum of exponentials. m97-style 128x128 tile, BK=64, 4 waves (2x2),
// global_load_lds width-16 staging, 16x16x32 bf16 MFMA.
// ---------------------------------------------------------------------------
__global__ __launch_bounds__(256) void simexp_kernel(
    const unsigned short* __restrict__ fn, float* __restrict__ rowsum) {
  __shared__ unsigned short ldsA[BM * BK];  // 16 KB, [row][k] row-major
  __shared__ unsigned short ldsB[BN * BK];  // 16 KB, [col][k] row-major (Fn rows)
  __shared__ float lds_rsum[BM];

  const int bid = blockIdx.x;
  const int chunk = bid & (NCHUNKS - 1);  // consecutive bids -> different XCDs,
  const int rm = bid >> 4;                // same chunk stays on one XCD (B-panel L2-hot)
  const int rowBase = rm * BM;
  const int tid = threadIdx.x;
  const int w = tid >> 6, lane = tid & 63;
  const int wr = w >> 1, wc = w & 1;      // wave grid 2x2, each wave owns 64x64
  const int l15 = lane & 15, l4 = lane >> 4;

  if (tid < BM) lds_rsum[tid] = 0.f;

  // staging decomposition: each global_load_lds moves 64 lanes * 16B = 1 KB = 8 rows
  const int srow = lane >> 3;           // row within an 8-row segment
  const int scolb = (lane & 7) * 16;    // byte offset within the 128B row

  for (int ct = 0; ct < CHUNK; ++ct) {
    const int colBase = (chunk * CHUNK + ct) * BN;
    f32x4 acc[4][4];
#pragma unroll
    for (int m = 0; m < 4; ++m)
#pragma unroll
      for (int n = 0; n < 4; ++n) acc[m][n] = (f32x4){0.f, 0.f, 0.f, 0.f};

    for (int kk = 0; kk < DDIM; kk += BK) {
      __syncthreads();  // previous tile's ds_reads done before overwrite
#pragma unroll
      for (int i = 0; i < 4; ++i) {
        const int seg = w * 4 + i;        // 16 segments of 8 rows across 4 waves
        const int row = seg * 8 + srow;
        const char* gA = (const char*)(fn + (size_t)(rowBase + row) * DDIM + kk) + scolb;
        const char* gB = (const char*)(fn + (size_t)(colBase + row) * DDIM + kk) + scolb;
        __builtin_amdgcn_global_load_lds((gu32*)gA, (lu32*)((char*)ldsA + seg * 1024), 16, 0, 0);
        __builtin_amdgcn_global_load_lds((gu32*)gB, (lu32*)((char*)ldsB + seg * 1024), 16, 0, 0);
      }
      __syncthreads();  // staged (compiler drains vmcnt before barrier)
#pragma unroll
      for (int ks = 0; ks < 2; ++ks) {
        bf16x8 af[4], bfr[4];
#pragma unroll
        for (int m = 0; m < 4; ++m)
          af[m] = *(const bf16x8*)(ldsA + (wr * 64 + m * 16 + l15) * BK + ks * 32 + l4 * 8);
#pragma unroll
        for (int n = 0; n < 4; ++n)
          bfr[n] = *(const bf16x8*)(ldsB + (wc * 64 + n * 16 + l15) * BK + ks * 32 + l4 * 8);
#pragma unroll
        for (int m = 0; m < 4; ++m)
#pragma unroll
          for (int n = 0; n < 4; ++n)
            acc[m][n] = __builtin_amdgcn_mfma_f32_16x16x32_bf16(af[m], bfr[n], acc[m][n], 0, 0, 0);
      }
    }

    // Epilogue: exp + masked per-row sum. C layout: col = l15, row = l4*4 + j.
    const bool diagTile = (rowBase == colBase);
#pragma unroll
    for (int m = 0; m < 4; ++m) {
      float ex[4] = {0.f, 0.f, 0.f, 0.f};
#pragma unroll
      for (int n = 0; n < 4; ++n) {
#pragma unroll
        for (int j = 0; j < 4; ++j) {
          float e = __expf(acc[m][n][j]);
          if (diagTile &&
              (wr * 64 + m * 16 + l4 * 4 + j) == (wc * 64 + n * 16 + l15))
            e = 0.f;  // mask self-similarity
          ex[j] += e;
        }
      }
#pragma unroll
      for (int j = 0; j < 4; ++j) {
        float s = ex[j];
        s += __shfl_xor(s, 1);
        s += __shfl_xor(s, 2);
        s += __shfl_xor(s, 4);
        s += __shfl_xor(s, 8);  // sum over the 16 columns held by this 16-lane group
        if (l15 == 0) atomicAdd(&lds_rsum[wr * 64 + m * 16 + l4 * 4 + j], s);
      }
    }
  }
  __syncthreads();
  if (tid < BM) atomicAdd(&rowsum[rowBase + tid], lds_rsum[tid]);
}

// ---------------------------------------------------------------------------
// Kernel 3: loss = mean_i( log(rowsum[i]) - dot(fn[i], fn[(i+B)%2B]) ).
// fn is pre-scaled by sqrt(1/T), so the dot is already pos/T.
// ---------------------------------------------------------------------------
__global__ __launch_bounds__(256) void finalize_kernel(
    const unsigned short* __restrict__ fn, const float* __restrict__ rowsum,
    float* __restrict__ out) {
  __shared__ float part[4];
  const int tid = threadIdx.x;
  const int w = tid >> 6, lane = tid & 63;
  const int i = blockIdx.x * 4 + w;
  const int j = (i + BHALF) & (NROWS - 1);
  const u16x8 va = *(const u16x8*)(fn + (size_t)i * DDIM + lane * 8);
  const u16x8 vb = *(const u16x8*)(fn + (size_t)j * DDIM + lane * 8);
  float dot = 0.f;
#pragma unroll
  for (int t = 0; t < 8; ++t) {
    float xa = __uint_as_float((unsigned)va[t] << 16);
    float xb = __uint_as_float((unsigned)vb[t] << 16);
    dot += xa * xb;
  }
#pragma unroll
  for (int m = 1; m < 64; m <<= 1) dot += __shfl_xor(dot, m);
  if (lane == 0) {
    part[w] = __logf(rowsum[i]) - dot;
  }
  __syncthreads();
  if (tid == 0) {
    float v = (part[0] + part[1] + part[2] + part[3]) * (1.0f / NROWS);
    atomicAdd(out, v);
  }
}

// ---------------------------------------------------------------------------
extern "C" void kernel_launch(void* const* d_in, const int* in_sizes, int n_in,
                              void* d_out, int out_size, void* d_ws, size_t ws_size,
                              hipStream_t stream) {
  const float* logits = (const float*)d_in[0];
  const float* label = (const float*)d_in[1];
  float* out = (float*)d_out;
  unsigned short* fn = (unsigned short*)d_ws;                       // 8 MB bf16 feats
  float* rowsum = (float*)((char*)d_ws + (size_t)NROWS * DDIM * 2); // 32 KB

  hipMemsetAsync(rowsum, 0, NROWS * sizeof(float), stream);
  hipMemsetAsync(out, 0, sizeof(float), stream);
  normalize_kernel<<<NROWS, 64, 0, stream>>>(logits, label, fn);
  simexp_kernel<<<GRID2, 256, 0, stream>>>(fn, rowsum);
  finalize_kernel<<<NROWS / 4, 256, 0, stream>>>(fn, rowsum, out);
}

// Round 2
// 139.617 us; speedup vs baseline: 1.5983x; 1.5983x over previous
//
#include <hip/hip_runtime.h>
#include <hip/hip_bf16.h>

// Problem constants
#define NROWS 8192   // 2B
#define BHALF 4096   // B
#define DDIM  512    // D

// GEMM tiling
#define BM 128
#define BK 64
#define NT (NROWS / BM)            // 64 tiles per side
#define NTRI (NT * (NT + 1) / 2)   // 2080 upper-triangle tiles

// sqrt(1/0.07): fold temperature into the normalized features so the MFMA
// accumulator is already sim/T.
#define FSCALE 3.7796447300922722f

typedef short bf16x8 __attribute__((ext_vector_type(8)));
typedef float f32x4 __attribute__((ext_vector_type(4)));
typedef unsigned short u16x8 __attribute__((ext_vector_type(8)));
typedef __attribute__((address_space(1))) unsigned int gu32;
typedef __attribute__((address_space(3))) unsigned int lu32;

// ---------------------------------------------------------------------------
// Kernel 1: L2-normalize rows of concat([logits,label]); store bf16 * FSCALE.
// 4 waves per block, one row per wave.
// ---------------------------------------------------------------------------
__global__ __launch_bounds__(256) void normalize_kernel(
    const float* __restrict__ logits, const float* __restrict__ label,
    unsigned short* __restrict__ fn) {
  const int w = threadIdx.x >> 6, lane = threadIdx.x & 63;
  const int row = blockIdx.x * 4 + w;
  const float* src = (row < BHALF) ? (logits + (size_t)row * DDIM)
                                   : (label + (size_t)(row - BHALF) * DDIM);
  const float4* s4 = (const float4*)src;
  float4 a = s4[lane * 2 + 0];
  float4 b = s4[lane * 2 + 1];
  float ss = a.x * a.x + a.y * a.y + a.z * a.z + a.w * a.w +
             b.x * b.x + b.y * b.y + b.z * b.z + b.w * b.w;
#pragma unroll
  for (int m = 1; m < 64; m <<= 1) ss += __shfl_xor(ss, m);
  const float inv = FSCALE / fmaxf(sqrtf(ss), 1e-12f);
  const float v[8] = {a.x, a.y, a.z, a.w, b.x, b.y, b.z, b.w};
  u16x8 o;
#pragma unroll
  for (int j = 0; j < 8; ++j) {
    float x = v[j] * inv;
    unsigned u = __float_as_uint(x);
    unsigned r = (u + 0x7fffu + ((u >> 16) & 1u)) >> 16;  // RNE to bf16
    o[j] = (unsigned short)r;
  }
  *(u16x8*)(fn + (size_t)row * DDIM + lane * 8) = o;
}

// ---------------------------------------------------------------------------
// Kernel 2: triangular fused sim/exp/row-sum. Each block owns one 128x128
// upper-triangle tile (rm, cn), cn >= rm. exp sums go to rowsum[rows] and
// (via symmetry, off-diagonal tiles only) rowsum[cols]. Tiles with
// cn == rm+32 carry the positive pairs on their local diagonal -> pos[].
// XOR-swizzled LDS (slot ^= row&7, both staging source and ds_read side)
// kills the 16-way bank conflicts of 128B-row tiles.
// ---------------------------------------------------------------------------
__global__ __launch_bounds__(256) void simexp_tri_kernel(
    const unsigned short* __restrict__ fn, float* __restrict__ rowsum,
    float* __restrict__ pos) {
  __shared__ unsigned short ldsA[BM * BK];  // 16 KB
  __shared__ unsigned short ldsB[BM * BK];  // 16 KB
  __shared__ float lds_rsum[BM];
  __shared__ float lds_csum[BM];

  // triangle index -> (rm, cn): enumerate from the bottom-right corner.
  const int u = (NTRI - 1) - (int)blockIdx.x;
  int k = (int)((sqrtf(8.f * (float)u + 1.f) - 1.f) * 0.5f);
  while ((k + 1) * (k + 2) / 2 <= u) ++k;
  while (k * (k + 1) / 2 > u) --k;
  const int rm = (NT - 1) - k;
  const int cn = (NT - 1) - (u - k * (k + 1) / 2);
  const int rowBase = rm * BM, colBase = cn * BM;
  const bool diag = (rm == cn);
  const bool posTile = (cn == rm + NT / 2);

  const int tid = threadIdx.x;
  const int w = tid >> 6, lane = tid & 63;
  const int wr = w >> 1, wc = w & 1;   // 2x2 wave grid, 64x64 each
  const int l15 = lane & 15, l4 = lane >> 4;

  if (tid < BM) { lds_rsum[tid] = 0.f; lds_csum[tid] = 0.f; }

  // staging: one global_load_lds = 64 lanes * 16B = 8 rows of 128B.
  // LDS dest is linear (lane*16); the GLOBAL slot is pre-swizzled so that
  // LDS slot s of row r holds global slot s ^ (r&7).
  const int r8 = lane >> 3;                    // row within 8-row segment
  const int sgbyte = ((lane & 7) ^ r8) * 16;   // swizzled source byte offset

  f32x4 acc[4][4];
#pragma unroll
  for (int m = 0; m < 4; ++m)
#pragma unroll
    for (int n = 0; n < 4; ++n) acc[m][n] = (f32x4){0.f, 0.f, 0.f, 0.f};

  for (int kk = 0; kk < DDIM; kk += BK) {
    __syncthreads();  // prior ds_reads done before overwrite
#pragma unroll
    for (int i = 0; i < 4; ++i) {
      const int seg = w * 4 + i;      // 16 segments of 8 rows
      const int row = seg * 8 + r8;
      const char* gA = (const char*)(fn + (size_t)(rowBase + row) * DDIM + kk) + sgbyte;
      const char* gB = (const char*)(fn + (size_t)(colBase + row) * DDIM + kk) + sgbyte;
      __builtin_amdgcn_global_load_lds((gu32*)gA, (lu32*)((char*)ldsA + seg * 1024), 16, 0, 0);
      __builtin_amdgcn_global_load_lds((gu32*)gB, (lu32*)((char*)ldsB + seg * 1024), 16, 0, 0);
    }
    __syncthreads();  // staged (compiler drains vmcnt before barrier)
#pragma unroll
    for (int ks = 0; ks < 2; ++ks) {
      bf16x8 af[4], bfr[4];
#pragma unroll
      for (int m = 0; m < 4; ++m) {
        const int r = wr * 64 + m * 16 + l15;
        af[m] = *(const bf16x8*)((const char*)ldsA + r * 128 + (((ks * 4 + l4) ^ (r & 7)) << 4));
      }
#pragma unroll
      for (int n = 0; n < 4; ++n) {
        const int r = wc * 64 + n * 16 + l15;
        bfr[n] = *(const bf16x8*)((const char*)ldsB + r * 128 + (((ks * 4 + l4) ^ (r & 7)) << 4));
      }
#pragma unroll
      for (int m = 0; m < 4; ++m)
#pragma unroll
        for (int n = 0; n < 4; ++n)
          acc[m][n] = __builtin_amdgcn_mfma_f32_16x16x32_bf16(af[m], bfr[n], acc[m][n], 0, 0, 0);
    }
  }

  // Epilogue. C layout: col = l15, row = l4*4 + j (verified round 1).
  float rs[4][4];  // per-lane row partials [m][j], summed over n
  float cs[4];     // per-lane col partials [n], summed over m,j
#pragma unroll
  for (int m = 0; m < 4; ++m)
#pragma unroll
    for (int j = 0; j < 4; ++j) rs[m][j] = 0.f;
#pragma unroll
  for (int n = 0; n < 4; ++n) cs[n] = 0.f;

#pragma unroll
  for (int m = 0; m < 4; ++m)
#pragma unroll
    for (int n = 0; n < 4; ++n)
#pragma unroll
      for (int j = 0; j < 4; ++j) {
        const int rl = wr * 64 + m * 16 + l4 * 4 + j;  // local row
        const int cl = wc * 64 + n * 16 + l15;         // local col
        const float v = acc[m][n][j];
        float e = __expf(v);
        if (diag && rl == cl) e = 0.f;  // mask self-similarity
        rs[m][j] += e;
        cs[n] += e;
        if (posTile && rl == cl) pos[rowBase + rl] = v;  // sim[i, i+B]/T
      }

  // row reduce over the 16 columns held per 16-lane group
#pragma unroll
  for (int m = 0; m < 4; ++m)
#pragma unroll
    for (int j = 0; j < 4; ++j) {
      float s = rs[m][j];
      s += __shfl_xor(s, 1);
      s += __shfl_xor(s, 2);
      s += __shfl_xor(s, 4);
      s += __shfl_xor(s, 8);
      if (l15 == 0) atomicAdd(&lds_rsum[wr * 64 + m * 16 + l4 * 4 + j], s);
    }
  // col reduce over the 4 l4 groups (rows), off-diagonal tiles only
  if (!diag) {
#pragma unroll
    for (int n = 0; n < 4; ++n) {
      float s = cs[n];
      s += __shfl_xor(s, 16);
      s += __shfl_xor(s, 32);
      if (l4 == 0) atomicAdd(&lds_csum[wc * 64 + n * 16 + l15], s);
    }
  }
  __syncthreads();
  if (tid < BM) {
    atomicAdd(&rowsum[rowBase + tid], lds_rsum[tid]);
    if (!diag) atomicAdd(&rowsum[colBase + tid], lds_csum[tid]);
  }
}

// ---------------------------------------------------------------------------
// Kernel 3: loss = mean_i( log(rowsum[i]) - pos[i mod B] ). Single block.
// ---------------------------------------------------------------------------
__global__ __launch_bounds__(1024) void reduce_kernel(
    const float* __restrict__ rowsum, const float* __restrict__ pos,
    float* __restrict__ out) {
  __shared__ float part[16];
  float a = 0.f;
  for (int i = threadIdx.x; i < NROWS; i += 1024)
    a += __logf(rowsum[i]) - pos[i & (BHALF - 1)];
#pragma unroll
  for (int m = 1; m < 64; m <<= 1) a += __shfl_xor(a, m);
  const int w = threadIdx.x >> 6, lane = threadIdx.x & 63;
  if (lane == 0) part[w] = a;
  __syncthreads();
  if (threadIdx.x == 0) {
    float t = 0.f;
#pragma unroll
    for (int i = 0; i < 16; ++i) t += part[i];
    out[0] = t * (1.0f / NROWS);
  }
}

// ---------------------------------------------------------------------------
extern "C" void kernel_launch(void* const* d_in, const int* in_sizes, int n_in,
                              void* d_out, int out_size, void* d_ws, size_t ws_size,
                              hipStream_t stream) {
  const float* logits = (const float*)d_in[0];
  const float* label = (const float*)d_in[1];
  float* out = (float*)d_out;
  unsigned short* fn = (unsigned short*)d_ws;                        // 8 MB bf16
  float* rowsum = (float*)((char*)d_ws + (size_t)NROWS * DDIM * 2);  // 32 KB
  float* pos = rowsum + NROWS;                                       // 16 KB

  hipMemsetAsync(rowsum, 0, NROWS * sizeof(float), stream);
  normalize_kernel<<<NROWS / 4, 256, 0, stream>>>(logits, label, fn);
  simexp_tri_kernel<<<NTRI, 256, 0, stream>>>(fn, rowsum, pos);
  reduce_kernel<<<1, 1024, 0, stream>>>(rowsum, pos, out);
}

// Round 3
// 137.233 us; speedup vs baseline: 1.6261x; 1.0174x over previous
//
#include <hip/hip_runtime.h>
#include <hip/hip_bf16.h>

// Problem constants
#define NROWS 8192   // 2B
#define BHALF 4096   // B
#define DDIM  512    // D

// GEMM tiling
#define BM 128
#define BK 64
#define KSTEPS (DDIM / BK)         // 8
#define NT (NROWS / BM)            // 64 tiles per side
#define NTRI (NT * (NT + 1) / 2)   // 2080 upper-triangle tiles
#define CPX (NTRI / 8)             // 260 blocks per XCD (2080 % 8 == 0 -> bijective)

// sqrt(1/0.07): fold temperature into the normalized features so the MFMA
// accumulator is already sim/T.
#define FSCALE 3.7796447300922722f

typedef short bf16x8 __attribute__((ext_vector_type(8)));
typedef float f32x4 __attribute__((ext_vector_type(4)));
typedef unsigned short u16x8 __attribute__((ext_vector_type(8)));
typedef __attribute__((address_space(1))) unsigned int gu32;
typedef __attribute__((address_space(3))) unsigned int lu32;

// ---------------------------------------------------------------------------
// Kernel 1: L2-normalize rows of concat([logits,label]); store bf16 * FSCALE.
// Also zeroes rowsum (blocks 0..7) and out (block 8) so no memsets needed.
// ---------------------------------------------------------------------------
__global__ __launch_bounds__(256) void normalize_kernel(
    const float* __restrict__ logits, const float* __restrict__ label,
    unsigned short* __restrict__ fn, float* __restrict__ rowsum,
    float* __restrict__ out) {
  if (blockIdx.x < 8)
    ((float4*)rowsum)[blockIdx.x * 256 + threadIdx.x] =
        make_float4(0.f, 0.f, 0.f, 0.f);
  if (blockIdx.x == 8 && threadIdx.x == 0) out[0] = 0.f;

  const int w = threadIdx.x >> 6, lane = threadIdx.x & 63;
  const int row = blockIdx.x * 4 + w;
  const float* src = (row < BHALF) ? (logits + (size_t)row * DDIM)
                                   : (label + (size_t)(row - BHALF) * DDIM);
  const float4* s4 = (const float4*)src;
  float4 a = s4[lane * 2 + 0];
  float4 b = s4[lane * 2 + 1];
  float ss = a.x * a.x + a.y * a.y + a.z * a.z + a.w * a.w +
             b.x * b.x + b.y * b.y + b.z * b.z + b.w * b.w;
#pragma unroll
  for (int m = 1; m < 64; m <<= 1) ss += __shfl_xor(ss, m);
  const float inv = FSCALE / fmaxf(sqrtf(ss), 1e-12f);
  const float v[8] = {a.x, a.y, a.z, a.w, b.x, b.y, b.z, b.w};
  u16x8 o;
#pragma unroll
  for (int j = 0; j < 8; ++j) {
    float x = v[j] * inv;
    unsigned u = __float_as_uint(x);
    unsigned r = (u + 0x7fffu + ((u >> 16) & 1u)) >> 16;  // RNE to bf16
    o[j] = (unsigned short)r;
  }
  *(u16x8*)(fn + (size_t)row * DDIM + lane * 8) = o;
}

// ---------------------------------------------------------------------------
// Kernel 2: triangular fused sim/exp/row-sum, double-buffered 2-phase
// pipeline (T3-minimal): issue next K-tile's global_load_lds BEFORE the
// current tile's ds_read+MFMA; one vmcnt(0)+barrier per step hides the
// load latency under compute. XOR-swizzled LDS (both-sides) keeps
// bank conflicts at 0. Upper-triangle tiles only; off-diagonal tiles
// scatter exp-sums to both row and (transposed) col sums. Tiles with
// cn == rm+32 carry pos[] on their local diagonal.
// ---------------------------------------------------------------------------
__global__ __launch_bounds__(256) void simexp_tri_kernel(
    const unsigned short* __restrict__ fn, float* __restrict__ rowsum,
    float* __restrict__ pos) {
  __shared__ unsigned short ldsA[2][BM * BK];  // 2 x 16 KB
  __shared__ unsigned short ldsB[2][BM * BK];  // 2 x 16 KB
  __shared__ float lds_rsum[BM];
  __shared__ float lds_csum[BM];

  // XCD-contiguous remap, then triangle index -> (rm, cn) from bottom-right.
  const int bid0 = (int)blockIdx.x;
  const int bid = (bid0 & 7) * CPX + (bid0 >> 3);
  const int u = (NTRI - 1) - bid;
  int k = (int)((sqrtf(8.f * (float)u + 1.f) - 1.f) * 0.5f);
  while ((k + 1) * (k + 2) / 2 <= u) ++k;
  while (k * (k + 1) / 2 > u) --k;
  const int rm = (NT - 1) - k;
  const int cn = (NT - 1) - (u - k * (k + 1) / 2);
  const int rowBase = rm * BM, colBase = cn * BM;
  const bool diag = (rm == cn);
  const bool posTile = (cn == rm + NT / 2);

  const int tid = threadIdx.x;
  const int w = tid >> 6, lane = tid & 63;
  const int wr = w >> 1, wc = w & 1;   // 2x2 wave grid, 64x64 each
  const int l15 = lane & 15, l4 = lane >> 4;

  if (tid < BM) { lds_rsum[tid] = 0.f; lds_csum[tid] = 0.f; }

  // staging: one global_load_lds = 64 lanes * 16B = 8 rows of 128B.
  // LDS dest linear; GLOBAL slot pre-swizzled so LDS slot s of row r holds
  // global slot s ^ (r&7).
  const int r8 = lane >> 3;
  const int sgbyte = ((lane & 7) ^ r8) * 16;

  auto stage = [&](unsigned short* dA, unsigned short* dB, int kk) {
#pragma unroll
    for (int i = 0; i < 4; ++i) {
      const int seg = w * 4 + i;  // 16 segments of 8 rows
      const int row = seg * 8 + r8;
      const char* gA =
          (const char*)(fn + (size_t)(rowBase + row) * DDIM + kk) + sgbyte;
      const char* gB =
          (const char*)(fn + (size_t)(colBase + row) * DDIM + kk) + sgbyte;
      __builtin_amdgcn_global_load_lds((gu32*)gA,
                                       (lu32*)((char*)dA + seg * 1024), 16, 0, 0);
      __builtin_amdgcn_global_load_lds((gu32*)gB,
                                       (lu32*)((char*)dB + seg * 1024), 16, 0, 0);
    }
  };

  f32x4 acc[4][4];
#pragma unroll
  for (int m = 0; m < 4; ++m)
#pragma unroll
    for (int n = 0; n < 4; ++n) acc[m][n] = (f32x4){0.f, 0.f, 0.f, 0.f};

  auto compute = [&](const unsigned short* sA, const unsigned short* sB) {
#pragma unroll
    for (int ks = 0; ks < 2; ++ks) {
      bf16x8 af[4], bfr[4];
#pragma unroll
      for (int m = 0; m < 4; ++m) {
        const int r = wr * 64 + m * 16 + l15;
        af[m] = *(const bf16x8*)((const char*)sA + r * 128 +
                                 (((ks * 4 + l4) ^ (r & 7)) << 4));
      }
#pragma unroll
      for (int n = 0; n < 4; ++n) {
        const int r = wc * 64 + n * 16 + l15;
        bfr[n] = *(const bf16x8*)((const char*)sB + r * 128 +
                                  (((ks * 4 + l4) ^ (r & 7)) << 4));
      }
#pragma unroll
      for (int m = 0; m < 4; ++m)
#pragma unroll
        for (int n = 0; n < 4; ++n)
          acc[m][n] = __builtin_amdgcn_mfma_f32_16x16x32_bf16(af[m], bfr[n],
                                                              acc[m][n], 0, 0, 0);
    }
  };

  // -------- pipelined K-loop --------
  stage(ldsA[0], ldsB[0], 0);
  __syncthreads();  // buf0 staged
#pragma unroll
  for (int t = 0; t < KSTEPS; t += 2) {
    if (t + 1 < KSTEPS) stage(ldsA[1], ldsB[1], (t + 1) * BK);  // prefetch
    compute(ldsA[0], ldsB[0]);
    __syncthreads();  // drains vmcnt(0): buf1 staged; lgkm: buf0 reads done
    if (t + 2 < KSTEPS) stage(ldsA[0], ldsB[0], (t + 2) * BK);  // prefetch
    compute(ldsA[1], ldsB[1]);
    __syncthreads();
  }

  // Epilogue. C layout: col = l15, row = l4*4 + j (verified round 1).
  float rs[4][4];
  float cs[4];
#pragma unroll
  for (int m = 0; m < 4; ++m)
#pragma unroll
    for (int j = 0; j < 4; ++j) rs[m][j] = 0.f;
#pragma unroll
  for (int n = 0; n < 4; ++n) cs[n] = 0.f;

#pragma unroll
  for (int m = 0; m < 4; ++m)
#pragma unroll
    for (int n = 0; n < 4; ++n)
#pragma unroll
      for (int j = 0; j < 4; ++j) {
        const int rl = wr * 64 + m * 16 + l4 * 4 + j;  // local row
        const int cl = wc * 64 + n * 16 + l15;         // local col
        const float v = acc[m][n][j];
        float e = __expf(v);
        if (diag && rl == cl) e = 0.f;  // mask self-similarity
        rs[m][j] += e;
        cs[n] += e;
        if (posTile && rl == cl) pos[rowBase + rl] = v;  // sim[i, i+B]/T
      }

#pragma unroll
  for (int m = 0; m < 4; ++m)
#pragma unroll
    for (int j = 0; j < 4; ++j) {
      float s = rs[m][j];
      s += __shfl_xor(s, 1);
      s += __shfl_xor(s, 2);
      s += __shfl_xor(s, 4);
      s += __shfl_xor(s, 8);
      if (l15 == 0) atomicAdd(&lds_rsum[wr * 64 + m * 16 + l4 * 4 + j], s);
    }
  if (!diag) {
#pragma unroll
    for (int n = 0; n < 4; ++n) {
      float s = cs[n];
      s += __shfl_xor(s, 16);
      s += __shfl_xor(s, 32);
      if (l4 == 0) atomicAdd(&lds_csum[wc * 64 + n * 16 + l15], s);
    }
  }
  __syncthreads();
  if (tid < BM) {
    atomicAdd(&rowsum[rowBase + tid], lds_rsum[tid]);
    if (!diag) atomicAdd(&rowsum[colBase + tid], lds_csum[tid]);
  }
}

// ---------------------------------------------------------------------------
// Kernel 3: loss += mean-part of ( log(rowsum[i]) - pos[i mod B] ), 32 blocks.
// ---------------------------------------------------------------------------
__global__ __launch_bounds__(256) void reduce_kernel(
    const float* __restrict__ rowsum, const float* __restrict__ pos,
    float* __restrict__ out) {
  __shared__ float part[4];
  const int i = blockIdx.x * 256 + threadIdx.x;
  float a = __logf(rowsum[i]) - pos[i & (BHALF - 1)];
#pragma unroll
  for (int m = 1; m < 64; m <<= 1) a += __shfl_xor(a, m);
  const int w = threadIdx.x >> 6, lane = threadIdx.x & 63;
  if (lane == 0) part[w] = a;
  __syncthreads();
  if (threadIdx.x == 0)
    atomicAdd(out, (part[0] + part[1] + part[2] + part[3]) * (1.0f / NROWS));
}

// ---------------------------------------------------------------------------
extern "C" void kernel_launch(void* const* d_in, const int* in_sizes, int n_in,
                              void* d_out, int out_size, void* d_ws, size_t ws_size,
                              hipStream_t stream) {
  const float* logits = (const float*)d_in[0];
  const float* label = (const float*)d_in[1];
  float* out = (float*)d_out;
  unsigned short* fn = (unsigned short*)d_ws;                        // 8 MB bf16
  float* rowsum = (float*)((char*)d_ws + (size_t)NROWS * DDIM * 2);  // 32 KB
  float* pos = rowsum + NROWS;                                       // 16 KB

  normalize_kernel<<<NROWS / 4, 256, 0, stream>>>(logits, label, fn, rowsum, out);
  simexp_tri_kernel<<<NTRI, 256, 0, stream>>>(fn, rowsum, pos);
  reduce_kernel<<<NROWS / 256, 256, 0, stream>>>(rowsum, pos, out);
}

// Round 4
// 129.406 us; speedup vs baseline: 1.7244x; 1.0605x over previous
//
#include <hip/hip_runtime.h>
#include <hip/hip_bf16.h>

// Problem constants
#define NROWS 8192   // 2B
#define BHALF 4096   // B
#define DDIM  512    // D

// GEMM tiling: 256x256 tile, 8 waves (2M x 4N), BK=64, 8-phase counted-vmcnt
#define BM 256
#define BK 64
#define KT (DDIM / BK)             // 8 K-tiles
#define NT (NROWS / BM)            // 32 tiles per side
#define NTRI (NT * (NT + 1) / 2)   // 528 upper-triangle tiles
#define CPX (NTRI / 8)             // 66 (528 % 8 == 0 -> bijective XCD remap)

// sqrt(1/0.07): fold temperature into the normalized features.
#define FSCALE 3.7796447300922722f

typedef short bf16x8 __attribute__((ext_vector_type(8)));
typedef float f32x4 __attribute__((ext_vector_type(4)));
typedef unsigned short u16x8 __attribute__((ext_vector_type(8)));
typedef __attribute__((address_space(1))) unsigned int gu32;
typedef __attribute__((address_space(3))) unsigned int lu32;

#define MFMA_(a, b, c) __builtin_amdgcn_mfma_f32_16x16x32_bf16(a, b, c, 0, 0, 0)
#define VMCNT(N) asm volatile("s_waitcnt vmcnt(" #N ")" ::: "memory")
#define LGKM0                                            \
  do {                                                   \
    asm volatile("s_waitcnt lgkmcnt(0)" ::: "memory");   \
    __builtin_amdgcn_sched_barrier(0);                   \
  } while (0)
#define BAR                                              \
  do {                                                   \
    __builtin_amdgcn_sched_barrier(0);                   \
    __builtin_amdgcn_s_barrier();                        \
    __builtin_amdgcn_sched_barrier(0);                   \
  } while (0)

// ---------------------------------------------------------------------------
// Kernel 1: L2-normalize rows of concat([logits,label]); store bf16 * FSCALE.
// Also zeroes rowsum (blocks 0..7) and out (block 8).
// ---------------------------------------------------------------------------
__global__ __launch_bounds__(256) void normalize_kernel(
    const float* __restrict__ logits, const float* __restrict__ label,
    unsigned short* __restrict__ fn, float* __restrict__ rowsum,
    float* __restrict__ out) {
  if (blockIdx.x < 8)
    ((float4*)rowsum)[blockIdx.x * 256 + threadIdx.x] =
        make_float4(0.f, 0.f, 0.f, 0.f);
  if (blockIdx.x == 8 && threadIdx.x == 0) out[0] = 0.f;

  const int w = threadIdx.x >> 6, lane = threadIdx.x & 63;
  const int row = blockIdx.x * 4 + w;
  const float* src = (row < BHALF) ? (logits + (size_t)row * DDIM)
                                   : (label + (size_t)(row - BHALF) * DDIM);
  const float4* s4 = (const float4*)src;
  float4 a = s4[lane * 2 + 0];
  float4 b = s4[lane * 2 + 1];
  float ss = a.x * a.x + a.y * a.y + a.z * a.z + a.w * a.w +
             b.x * b.x + b.y * b.y + b.z * b.z + b.w * b.w;
#pragma unroll
  for (int m = 1; m < 64; m <<= 1) ss += __shfl_xor(ss, m);
  const float inv = FSCALE / fmaxf(sqrtf(ss), 1e-12f);
  const float v[8] = {a.x, a.y, a.z, a.w, b.x, b.y, b.z, b.w};
  u16x8 o;
#pragma unroll
  for (int j = 0; j < 8; ++j) {
    float x = v[j] * inv;
    unsigned u = __float_as_uint(x);
    unsigned r = (u + 0x7fffu + ((u >> 16) & 1u)) >> 16;  // RNE to bf16
    o[j] = (unsigned short)r;
  }
  *(u16x8*)(fn + (size_t)row * DDIM + lane * 8) = o;
}

// ---------------------------------------------------------------------------
// Kernel 2: triangular fused sim/exp/row-sum, 256^2 tile, 8-phase schedule
// with counted vmcnt (T3+T4), setprio around MFMA (T5), XOR-swizzled LDS
// (T2, both-sides), XCD-contiguous remap (T1).
//
// Staging order per K-tile (8 issues of 8KB, 2 per phase):
//   B0,B1 (P0) B2,B3 (P1) A0,A2 (P2) A1,A3 (P3)
//   where A0=rows 0-63, A1=64-127, A2=128-191, A3=192-255 (same for B).
// Derived waits: end-P1 vmcnt(4) completes current tile's A1,A3 (needed by
// P2/P3 reads); end-P3 vmcnt(2) completes next tile's B*+A0+A2 (needed by
// its P0/P1 reads). Never 0 except the peeled last tile.
// ---------------------------------------------------------------------------
__global__ __launch_bounds__(512) void simexp_tri_kernel(
    const unsigned short* __restrict__ fn, float* __restrict__ rowsum,
    float* __restrict__ pos) {
  extern __shared__ char lds[];  // 2 bufs x (A 32KB | B 32KB) = 128 KB
  __shared__ float lds_rsum[BM];
  __shared__ float lds_csum[BM];

  // XCD remap, then triangle index -> (rm, cn) from bottom-right.
  const int bid0 = (int)blockIdx.x;
  const int bid = (bid0 & 7) * CPX + (bid0 >> 3);
  const int u = (NTRI - 1) - bid;
  int k = (int)((sqrtf(8.f * (float)u + 1.f) - 1.f) * 0.5f);
  while ((k + 1) * (k + 2) / 2 <= u) ++k;
  while (k * (k + 1) / 2 > u) --k;
  const int rm = (NT - 1) - k;
  const int cn = (NT - 1) - (u - k * (k + 1) / 2);
  const int rowBase = rm * BM, colBase = cn * BM;
  const bool diag = (rm == cn);
  const bool posTile = (cn == rm + NT / 2);

  const int tid = threadIdx.x;
  const int w = tid >> 6, lane = tid & 63;
  const int wr = w >> 2, wc = w & 3;   // wave grid 2x4; wave owns 128x64 of C
  const int l15 = lane & 15, l4 = lane >> 4;

  if (tid < BM) { lds_rsum[tid] = 0.f; lds_csum[tid] = 0.f; }

  // one stage issue = 512 thr x 16B = 8KB = 64 rows of 128B; wave w covers
  // rows R+w*8 .. R+w*8+7. LDS dest linear; global slot pre-swizzled so LDS
  // slot s of row r holds global slot s ^ (r&7).
  const int r8 = lane >> 3;
  const int sw16 = ((lane & 7) ^ r8) << 4;

  auto stageA = [&](int d, int kk, int R) {
    const char* g =
        (const char*)(fn + (size_t)(rowBase + R + w * 8 + r8) * DDIM + kk) + sw16;
    __builtin_amdgcn_global_load_lds(
        (gu32*)g, (lu32*)(lds + d * 65536 + (R + w * 8) * 128), 16, 0, 0);
  };
  auto stageB = [&](int d, int kk, int R) {
    const char* g =
        (const char*)(fn + (size_t)(colBase + R + w * 8 + r8) * DDIM + kk) + sw16;
    __builtin_amdgcn_global_load_lds(
        (gu32*)g, (lu32*)(lds + d * 65536 + 32768 + (R + w * 8) * 128), 16, 0, 0);
  };
  auto readA = [&](int d, int m, int ks) -> bf16x8 {
    const int r = wr * 128 + m * 16 + l15;
    return *(const bf16x8*)(lds + d * 65536 + r * 128 +
                            (((ks * 4 + l4) ^ (r & 7)) << 4));
  };
  auto readB = [&](int d, int n, int ks) -> bf16x8 {
    const int r = wc * 64 + n * 16 + l15;
    return *(const bf16x8*)(lds + d * 65536 + 32768 + r * 128 +
                            (((ks * 4 + l4) ^ (r & 7)) << 4));
  };

  f32x4 acc[8][4];
#pragma unroll
  for (int m = 0; m < 8; ++m)
#pragma unroll
    for (int n = 0; n < 4; ++n) acc[m][n] = (f32x4){0.f, 0.f, 0.f, 0.f};

#define PHASE0(STAGES)                                                    \
  {                                                                       \
    _Pragma("unroll") for (int n = 0; n < 4; ++n) {                       \
      bf[n][0] = readB(d, n, 0);                                          \
      bf[n][1] = readB(d, n, 1);                                          \
    }                                                                     \
    bf16x8 a00 = readA(d, 0, 0), a01 = readA(d, 0, 1);                    \
    bf16x8 a10 = readA(d, 1, 0), a11 = readA(d, 1, 1);                    \
    STAGES;                                                               \
    BAR;                                                                  \
    LGKM0;                                                                \
    __builtin_amdgcn_s_setprio(1);                                        \
    _Pragma("unroll") for (int n = 0; n < 4; ++n) {                       \
      acc[0][n] = MFMA_(a00, bf[n][0], acc[0][n]);                        \
      acc[1][n] = MFMA_(a10, bf[n][0], acc[1][n]);                        \
    }                                                                     \
    _Pragma("unroll") for (int n = 0; n < 4; ++n) {                       \
      acc[0][n] = MFMA_(a01, bf[n][1], acc[0][n]);                        \
      acc[1][n] = MFMA_(a11, bf[n][1], acc[1][n]);                        \
    }                                                                     \
    __builtin_amdgcn_s_setprio(0);                                        \
    BAR;                                                                  \
  }

#define PHASE(P, STAGES, TAILWAIT)                                        \
  {                                                                       \
    bf16x8 a00 = readA(d, 2 * (P), 0), a01 = readA(d, 2 * (P), 1);        \
    bf16x8 a10 = readA(d, 2 * (P) + 1, 0), a11 = readA(d, 2 * (P) + 1, 1);\
    STAGES;                                                               \
    BAR;                                                                  \
    LGKM0;                                                                \
    __builtin_amdgcn_s_setprio(1);                                        \
    _Pragma("unroll") for (int n = 0; n < 4; ++n) {                       \
      acc[2 * (P)][n] = MFMA_(a00, bf[n][0], acc[2 * (P)][n]);            \
      acc[2 * (P) + 1][n] = MFMA_(a10, bf[n][0], acc[2 * (P) + 1][n]);    \
    }                                                                     \
    _Pragma("unroll") for (int n = 0; n < 4; ++n) {                       \
      acc[2 * (P)][n] = MFMA_(a01, bf[n][1], acc[2 * (P)][n]);            \
      acc[2 * (P) + 1][n] = MFMA_(a11, bf[n][1], acc[2 * (P) + 1][n]);    \
    }                                                                     \
    __builtin_amdgcn_s_setprio(0);                                        \
    TAILWAIT;                                                             \
    BAR;                                                                  \
  }

  // Prologue: stage tile 0 in wait-order; leave A1,A3 in flight.
  stageB(0, 0, 0);  stageB(0, 0, 64); stageB(0, 0, 128); stageB(0, 0, 192);
  stageA(0, 0, 0);  stageA(0, 0, 128);
  stageA(0, 0, 64); stageA(0, 0, 192);
  VMCNT(2);
  BAR;

  for (int t = 0; t < KT - 1; ++t) {
    const int d = t & 1, o = d ^ 1;
    const int kn = (t + 1) * BK;
    bf16x8 bf[4][2];
    PHASE0(stageB(o, kn, 0); stageB(o, kn, 64));
    PHASE(1, stageB(o, kn, 128); stageB(o, kn, 192), VMCNT(4));
    PHASE(2, stageA(o, kn, 0); stageA(o, kn, 128), (void)0);
    PHASE(3, stageA(o, kn, 64); stageA(o, kn, 192), VMCNT(2));
  }
  {  // peeled last tile: no staging; drain A1,A3 before P2.
    const int d = (KT - 1) & 1;
    bf16x8 bf[4][2];
    PHASE0((void)0);
    PHASE(1, (void)0, VMCNT(0));
    PHASE(2, (void)0, (void)0);
    PHASE(3, (void)0, (void)0);
  }
#undef PHASE0
#undef PHASE

  // Epilogue. C frag layout: col = l15, row = l4*4 + j (verified r1-r3).
  float rs[8][4];
  float cs[4];
#pragma unroll
  for (int m = 0; m < 8; ++m)
#pragma unroll
    for (int j = 0; j < 4; ++j) rs[m][j] = 0.f;
#pragma unroll
  for (int n = 0; n < 4; ++n) cs[n] = 0.f;

#pragma unroll
  for (int m = 0; m < 8; ++m)
#pragma unroll
    for (int n = 0; n < 4; ++n)
#pragma unroll
      for (int j = 0; j < 4; ++j) {
        const int rl = wr * 128 + m * 16 + l4 * 4 + j;  // local row
        const int cl = wc * 64 + n * 16 + l15;          // local col
        const float v = acc[m][n][j];
        float e = __expf(v);
        if (diag && rl == cl) e = 0.f;  // mask self-similarity
        rs[m][j] += e;
        cs[n] += e;
        if (posTile && rl == cl) pos[rowBase + rl] = v;  // sim[i, i+B]/T
      }

#pragma unroll
  for (int m = 0; m < 8; ++m)
#pragma unroll
    for (int j = 0; j < 4; ++j) {
      float s = rs[m][j];
      s += __shfl_xor(s, 1);
      s += __shfl_xor(s, 2);
      s += __shfl_xor(s, 4);
      s += __shfl_xor(s, 8);
      if (l15 == 0)
        atomicAdd(&lds_rsum[wr * 128 + m * 16 + l4 * 4 + j], s);
    }
  if (!diag) {
#pragma unroll
    for (int n = 0; n < 4; ++n) {
      float s = cs[n];
      s += __shfl_xor(s, 16);
      s += __shfl_xor(s, 32);
      if (l4 == 0) atomicAdd(&lds_csum[wc * 64 + n * 16 + l15], s);
    }
  }
  __syncthreads();
  if (tid < BM) {
    atomicAdd(&rowsum[rowBase + tid], lds_rsum[tid]);
    if (!diag) atomicAdd(&rowsum[colBase + tid], lds_csum[tid]);
  }
}

// ---------------------------------------------------------------------------
// Kernel 3: loss += mean-part of ( log(rowsum[i]) - pos[i mod B] ), 32 blocks.
// ---------------------------------------------------------------------------
__global__ __launch_bounds__(256) void reduce_kernel(
    const float* __restrict__ rowsum, const float* __restrict__ pos,
    float* __restrict__ out) {
  __shared__ float part[4];
  const int i = blockIdx.x * 256 + threadIdx.x;
  float a = __logf(rowsum[i]) - pos[i & (BHALF - 1)];
#pragma unroll
  for (int m = 1; m < 64; m <<= 1) a += __shfl_xor(a, m);
  const int w = threadIdx.x >> 6, lane = threadIdx.x & 63;
  if (lane == 0) part[w] = a;
  __syncthreads();
  if (threadIdx.x == 0)
    atomicAdd(out, (part[0] + part[1] + part[2] + part[3]) * (1.0f / NROWS));
}

// ---------------------------------------------------------------------------
extern "C" void kernel_launch(void* const* d_in, const int* in_sizes, int n_in,
                              void* d_out, int out_size, void* d_ws, size_t ws_size,
                              hipStream_t stream) {
  const float* logits = (const float*)d_in[0];
  const float* label = (const float*)d_in[1];
  float* out = (float*)d_out;
  unsigned short* fn = (unsigned short*)d_ws;                        // 8 MB bf16
  float* rowsum = (float*)((char*)d_ws + (size_t)NROWS * DDIM * 2);  // 32 KB
  float* pos = rowsum + NROWS;                                       // 16 KB

  normalize_kernel<<<NROWS / 4, 256, 0, stream>>>(logits, label, fn, rowsum, out);
  simexp_tri_kernel<<<NTRI, 512, 2 * 65536, stream>>>(fn, rowsum, pos);
  reduce_kernel<<<NROWS / 256, 256, 0, stream>>>(rowsum, pos, out);
}